// Round 1
// baseline (346.846 us; speedup 1.0000x reference)
//
#include <hip/hip_runtime.h>
#include <hip/hip_bf16.h>
#include <math.h>

#define B_  64
#define N_  512
#define H_  512
#define NQ  8
#define NL  4

typedef __bf16 bf16;
typedef float  f32x4  __attribute__((ext_vector_type(4)));
typedef bf16   bf16x8 __attribute__((ext_vector_type(8)));

#define BK    32
#define PITCH 40   // LDS pitch in bf16 elems: 80 B, 16B-aligned, breaks pow2 bank stride

// ---------------------------------------------------------------------------
// GEMM1: P[b] = bf16( adj @ x[b] )   (A = adj fp32 shared, B = x[b] fp32 K-major)
// ---------------------------------------------------------------------------
__global__ __launch_bounds__(256) void gemm1_kernel(const float* __restrict__ adj,
                                                    const float* __restrict__ x,
                                                    bf16* __restrict__ P) {
    __shared__ bf16 As[128 * PITCH];  // [m][k]
    __shared__ bf16 Bs[128 * PITCH];  // [n][k]  (x staged transposed)
    const int b    = blockIdx.y;
    const int tile = blockIdx.x;            // 16 tiles: 4x4 of 128x128
    const int i0   = (tile >> 2) * 128;
    const int h0   = (tile & 3) * 128;
    const int t    = threadIdx.x;
    const int lane = t & 63;
    const int wid  = t >> 6;
    const int wr   = (wid >> 1) * 64;
    const int wc   = (wid & 1) * 64;
    const int l15  = lane & 15;
    const int quad = lane >> 4;

    f32x4 acc[4][4];
    for (int i = 0; i < 4; i++)
        for (int j = 0; j < 4; j++) acc[i][j] = (f32x4)(0.0f);

    const float* xb = x + (size_t)b * N_ * H_;

    for (int k0 = 0; k0 < N_; k0 += BK) {
        // A tile: adj[i0+row][k0 + ch*4 ..], fp32 -> bf16. 1024 float4 chunks.
        for (int c = t; c < 1024; c += 256) {
            int row = c >> 3, ch = c & 7;
            const float4 v = *(const float4*)(adj + (i0 + row) * N_ + k0 + ch * 4);
            bf16* d = &As[row * PITCH + ch * 4];
            d[0] = (bf16)v.x; d[1] = (bf16)v.y; d[2] = (bf16)v.z; d[3] = (bf16)v.w;
        }
        // B tile (transposed stage): Bs[n][k] = x[b][k0+kk][h0+n]
        for (int c = t; c < 1024; c += 256) {
            int kk = c >> 5, nv = (c & 31) * 4;
            const float4 v = *(const float4*)(xb + (k0 + kk) * H_ + h0 + nv);
            Bs[(nv + 0) * PITCH + kk] = (bf16)v.x;
            Bs[(nv + 1) * PITCH + kk] = (bf16)v.y;
            Bs[(nv + 2) * PITCH + kk] = (bf16)v.z;
            Bs[(nv + 3) * PITCH + kk] = (bf16)v.w;
        }
        __syncthreads();
        bf16x8 af[4], bfr[4];
        for (int mt = 0; mt < 4; mt++)
            af[mt] = *(const bf16x8*)&As[(wr + mt * 16 + l15) * PITCH + quad * 8];
        for (int nt = 0; nt < 4; nt++)
            bfr[nt] = *(const bf16x8*)&Bs[(wc + nt * 16 + l15) * PITCH + quad * 8];
        for (int mt = 0; mt < 4; mt++)
            for (int nt = 0; nt < 4; nt++)
                acc[mt][nt] = __builtin_amdgcn_mfma_f32_16x16x32_bf16(af[mt], bfr[nt], acc[mt][nt], 0, 0, 0);
        __syncthreads();
    }

    bf16* Pb = P + (size_t)b * N_ * H_;
    for (int mt = 0; mt < 4; mt++) {
        int row = i0 + wr + mt * 16 + quad * 4;
        for (int nt = 0; nt < 4; nt++) {
            int col = h0 + wc + nt * 16 + l15;
            for (int r = 0; r < 4; r++)
                Pb[(size_t)(row + r) * H_ + col] = (bf16)acc[mt][nt][r];
        }
    }
}

// ---------------------------------------------------------------------------
// GEMM2: out[b] = gelu( P[b] @ W^T + bias )   (A = P bf16, B = W fp32 BT layout)
// ---------------------------------------------------------------------------
__global__ __launch_bounds__(256) void gemm2_kernel(const bf16* __restrict__ P,
                                                    const float* __restrict__ W,
                                                    const float* __restrict__ bias,
                                                    float* __restrict__ out) {
    __shared__ bf16 As[128 * PITCH];
    __shared__ bf16 Bs[128 * PITCH];
    const int b    = blockIdx.y;
    const int tile = blockIdx.x;
    const int i0   = (tile >> 2) * 128;
    const int h0   = (tile & 3) * 128;
    const int t    = threadIdx.x;
    const int lane = t & 63;
    const int wid  = t >> 6;
    const int wr   = (wid >> 1) * 64;
    const int wc   = (wid & 1) * 64;
    const int l15  = lane & 15;
    const int quad = lane >> 4;

    f32x4 acc[4][4];
    for (int i = 0; i < 4; i++)
        for (int j = 0; j < 4; j++) acc[i][j] = (f32x4)(0.0f);

    const bf16* Pb = P + (size_t)b * N_ * H_;

    for (int k0 = 0; k0 < N_; k0 += BK) {
        // A tile: straight bf16 copy, 512 chunks of 8 bf16 (16 B)
        for (int c = t; c < 512; c += 256) {
            int row = c >> 2, ch = c & 3;
            bf16x8 v = *(const bf16x8*)(Pb + (size_t)(i0 + row) * H_ + k0 + ch * 8);
            *(bf16x8*)&As[row * PITCH + ch * 8] = v;
        }
        // B tile: Bs[n][k] = W[h0+n][k0+..] fp32 -> bf16 (W is already n-major)
        for (int c = t; c < 1024; c += 256) {
            int row = c >> 3, ch = c & 7;
            const float4 v = *(const float4*)(W + (h0 + row) * H_ + k0 + ch * 4);
            bf16* d = &Bs[row * PITCH + ch * 4];
            d[0] = (bf16)v.x; d[1] = (bf16)v.y; d[2] = (bf16)v.z; d[3] = (bf16)v.w;
        }
        __syncthreads();
        bf16x8 af[4], bfr[4];
        for (int mt = 0; mt < 4; mt++)
            af[mt] = *(const bf16x8*)&As[(wr + mt * 16 + l15) * PITCH + quad * 8];
        for (int nt = 0; nt < 4; nt++)
            bfr[nt] = *(const bf16x8*)&Bs[(wc + nt * 16 + l15) * PITCH + quad * 8];
        for (int mt = 0; mt < 4; mt++)
            for (int nt = 0; nt < 4; nt++)
                acc[mt][nt] = __builtin_amdgcn_mfma_f32_16x16x32_bf16(af[mt], bfr[nt], acc[mt][nt], 0, 0, 0);
        __syncthreads();
    }

    float* ob = out + (size_t)b * N_ * H_;
    for (int mt = 0; mt < 4; mt++) {
        int row = i0 + wr + mt * 16 + quad * 4;
        for (int nt = 0; nt < 4; nt++) {
            int col = h0 + wc + nt * 16 + l15;
            float bv = bias[col];
            for (int r = 0; r < 4; r++) {
                float v = acc[mt][nt][r] + bv;
                float g = 0.5f * v * (1.0f + erff(v * 0.70710678118654752f));
                ob[(size_t)(row + r) * H_ + col] = g;
            }
        }
    }
}

// ---------------------------------------------------------------------------
// Quantum: per batch, x_qin = tanh(tgt@pre_w^T + pre_b)*pi; simulate 8-qubit
// circuit; out[b,0,:] = zs @ post_w^T + post_b.  1 thread per amplitude.
// Flat index bit (7-w) <-> qubit w.
// ---------------------------------------------------------------------------
__global__ __launch_bounds__(256) void quantum_kernel(float* __restrict__ out,
                                                      const float* __restrict__ pre_w,
                                                      const float* __restrict__ pre_b,
                                                      const float* __restrict__ post_w,
                                                      const float* __restrict__ post_b,
                                                      const float* __restrict__ qw) {
    __shared__ float  tgt[512];
    __shared__ float2 st[256];
    __shared__ float  red[256];
    __shared__ float  zs[NQ];
    __shared__ float  ang[NQ];
    const int b = blockIdx.x;
    const int t = threadIdx.x;
    float* row0 = out + (size_t)b * N_ * H_;

    tgt[t]       = row0[t];
    tgt[t + 256] = row0[t + 256];
    __syncthreads();

    // x_qin
    for (int q = 0; q < NQ; q++) {
        red[t] = tgt[t] * pre_w[q * H_ + t] + tgt[t + 256] * pre_w[q * H_ + 256 + t];
        __syncthreads();
        for (int s = 128; s > 0; s >>= 1) {
            if (t < s) red[t] += red[t + s];
            __syncthreads();
        }
        if (t == 0) ang[q] = tanhf(red[0] + pre_b[q]) * 3.14159265358979323846f;
        __syncthreads();
    }

    // |0...0>
    st[t] = (t == 0) ? make_float2(1.0f, 0.0f) : make_float2(0.0f, 0.0f);
    __syncthreads();

    // RY(ang[w]) on each qubit. U = [[c,-s],[s,c]] (real).
    for (int w = 0; w < NQ; w++) {
        float th = 0.5f * ang[w];
        float c = cosf(th), s = sinf(th);
        int mask = 1 << (7 - w);
        float2 a = st[t];
        float2 p = st[t ^ mask];
        __syncthreads();
        float2 nv;
        if (t & mask) { nv.x = c * a.x + s * p.x; nv.y = c * a.y + s * p.y; }
        else          { nv.x = c * a.x - s * p.x; nv.y = c * a.y - s * p.y; }
        st[t] = nv;
        __syncthreads();
    }

    for (int l = 0; l < NL; l++) {
        // RX(qw[l,w]): new = c*a - i*s*p  (same form for both halves)
        for (int w = 0; w < NQ; w++) {
            float th = 0.5f * qw[l * NQ + w];
            float c = cosf(th), s = sinf(th);
            int mask = 1 << (7 - w);
            float2 a = st[t], p = st[t ^ mask];
            __syncthreads();
            float2 nv;
            nv.x = c * a.x + s * p.y;
            nv.y = c * a.y - s * p.x;
            st[t] = nv;
            __syncthreads();
        }
        // CNOT ring: control w, target (w+1)%8
        for (int w = 0; w < NQ; w++) {
            int cm = 1 << (7 - w);
            int tm = 1 << (7 - ((w + 1) & 7));
            float2 a = st[t], p = st[t ^ tm];
            __syncthreads();
            st[t] = (t & cm) ? p : a;
            __syncthreads();
        }
    }

    // <Z_q>
    float pr = st[t].x * st[t].x + st[t].y * st[t].y;
    for (int q = 0; q < NQ; q++) {
        red[t] = (t & (1 << (7 - q))) ? -pr : pr;
        __syncthreads();
        for (int s = 128; s > 0; s >>= 1) {
            if (t < s) red[t] += red[t + s];
            __syncthreads();
        }
        if (t == 0) zs[q] = red[0];
        __syncthreads();
    }

    // out[b,0,h] = sum_q zs[q] * post_w[h,q] + post_b[h]
    for (int h = t; h < H_; h += 256) {
        float v = post_b[h];
        for (int q = 0; q < NQ; q++) v += zs[q] * post_w[h * NQ + q];
        row0[h] = v;
    }
}

// ---------------------------------------------------------------------------
extern "C" void kernel_launch(void* const* d_in, const int* in_sizes, int n_in,
                              void* d_out, int out_size, void* d_ws, size_t ws_size,
                              hipStream_t stream) {
    const float* x        = (const float*)d_in[0];  // (64,512,512)
    const float* norm_adj = (const float*)d_in[1];  // (512,512)
    const float* W_gcn_w  = (const float*)d_in[2];  // (512,512)
    const float* W_gcn_b  = (const float*)d_in[3];  // (512,)
    const float* pre_w    = (const float*)d_in[4];  // (8,512)
    const float* pre_b    = (const float*)d_in[5];  // (8,)
    const float* post_w   = (const float*)d_in[6];  // (512,8)
    const float* post_b   = (const float*)d_in[7];  // (512,)
    const float* q_w      = (const float*)d_in[8];  // (4,8)
    float* out = (float*)d_out;
    bf16* P = (bf16*)d_ws;                          // 64*512*512 bf16 = 32 MiB

    dim3 grid(16, B_);
    gemm1_kernel<<<grid, 256, 0, stream>>>(norm_adj, x, P);
    gemm2_kernel<<<grid, 256, 0, stream>>>(P, W_gcn_w, W_gcn_b, out);
    quantum_kernel<<<B_, 256, 0, stream>>>(out, pre_w, pre_b, post_w, post_b, q_w);
}

// Round 2
// 264.138 us; speedup vs baseline: 1.3131x; 1.3131x over previous
//
#include <hip/hip_runtime.h>
#include <hip/hip_bf16.h>
#include <math.h>

#define B_  64
#define N_  512
#define H_  512
#define NQ  8
#define NL  4

typedef __bf16 bf16;
typedef float  f32x4  __attribute__((ext_vector_type(4)));
typedef bf16   bf16x8 __attribute__((ext_vector_type(8)));

#define BK    32
#define PITCH 40   // LDS pitch (bf16 elems): 80 B rows; start-bank stride 20 -> balanced

// ---------------------------------------------------------------------------
// GEMM1: P[b] = bf16( adj @ x[b] )
// B-stage: each thread loads 8 k-strided fp32 at fixed n -> one ds_write_b128.
// ---------------------------------------------------------------------------
__global__ __launch_bounds__(256) void gemm1_kernel(const float* __restrict__ adj,
                                                    const float* __restrict__ x,
                                                    bf16* __restrict__ P) {
    __shared__ bf16 As[128 * PITCH];  // [m][k]
    __shared__ bf16 Bs[128 * PITCH];  // [n][k]
    const int b    = blockIdx.y;
    const int tile = blockIdx.x;
    const int i0   = (tile >> 2) * 128;
    const int h0   = (tile & 3) * 128;
    const int t    = threadIdx.x;
    const int lane = t & 63;
    const int wid  = t >> 6;
    const int wr   = (wid >> 1) * 64;
    const int wc   = (wid & 1) * 64;
    const int l15  = lane & 15;
    const int quad = lane >> 4;

    f32x4 acc[4][4];
    for (int i = 0; i < 4; i++)
        for (int j = 0; j < 4; j++) acc[i][j] = (f32x4)(0.0f);

    const float* xb = x + (size_t)b * N_ * H_;

    for (int k0 = 0; k0 < N_; k0 += BK) {
        // A tile: 512 chunks of 8 k; 2 float4 loads -> 1 ds_write_b128
        for (int c = t; c < 512; c += 256) {
            int row = c >> 2, ch = c & 3;
            const float* s = adj + (i0 + row) * N_ + k0 + ch * 8;
            const float4 v0 = *(const float4*)s;
            const float4 v1 = *(const float4*)(s + 4);
            bf16x8 p;
            p[0] = (bf16)v0.x; p[1] = (bf16)v0.y; p[2] = (bf16)v0.z; p[3] = (bf16)v0.w;
            p[4] = (bf16)v1.x; p[5] = (bf16)v1.y; p[6] = (bf16)v1.z; p[7] = (bf16)v1.w;
            *(bf16x8*)&As[row * PITCH + ch * 8] = p;
        }
        // B tile (transpose stage, conflict-free): thread owns (n, k-group g),
        // loads 8 k-strided floats (coalesced across lanes in n), writes b128.
        for (int it = 0; it < 2; it++) {
            int idx = t + it * 256;            // 0..511
            int n   = idx & 127;
            int g   = idx >> 7;                // 0..3
            const float* s = xb + (size_t)(k0 + g * 8) * H_ + h0 + n;
            bf16x8 p;
            p[0] = (bf16)s[0 * H_]; p[1] = (bf16)s[1 * H_];
            p[2] = (bf16)s[2 * H_]; p[3] = (bf16)s[3 * H_];
            p[4] = (bf16)s[4 * H_]; p[5] = (bf16)s[5 * H_];
            p[6] = (bf16)s[6 * H_]; p[7] = (bf16)s[7 * H_];
            *(bf16x8*)&Bs[n * PITCH + g * 8] = p;
        }
        __syncthreads();
        bf16x8 af[4], bfr[4];
        for (int mt = 0; mt < 4; mt++)
            af[mt] = *(const bf16x8*)&As[(wr + mt * 16 + l15) * PITCH + quad * 8];
        for (int nt = 0; nt < 4; nt++)
            bfr[nt] = *(const bf16x8*)&Bs[(wc + nt * 16 + l15) * PITCH + quad * 8];
        for (int mt = 0; mt < 4; mt++)
            for (int nt = 0; nt < 4; nt++)
                acc[mt][nt] = __builtin_amdgcn_mfma_f32_16x16x32_bf16(af[mt], bfr[nt], acc[mt][nt], 0, 0, 0);
        __syncthreads();
    }

    bf16* Pb = P + (size_t)b * N_ * H_;
    for (int mt = 0; mt < 4; mt++) {
        int row = i0 + wr + mt * 16 + quad * 4;
        for (int nt = 0; nt < 4; nt++) {
            int col = h0 + wc + nt * 16 + l15;
            for (int r = 0; r < 4; r++)
                Pb[(size_t)(row + r) * H_ + col] = (bf16)acc[mt][nt][r];
        }
    }
}

// ---------------------------------------------------------------------------
// GEMM2: out[b] = gelu( P[b] @ W^T + bias )   (W is n-major: no transpose)
// ---------------------------------------------------------------------------
__global__ __launch_bounds__(256) void gemm2_kernel(const bf16* __restrict__ P,
                                                    const float* __restrict__ W,
                                                    const float* __restrict__ bias,
                                                    float* __restrict__ out) {
    __shared__ bf16 As[128 * PITCH];
    __shared__ bf16 Bs[128 * PITCH];
    const int b    = blockIdx.y;
    const int tile = blockIdx.x;
    const int i0   = (tile >> 2) * 128;
    const int h0   = (tile & 3) * 128;
    const int t    = threadIdx.x;
    const int lane = t & 63;
    const int wid  = t >> 6;
    const int wr   = (wid >> 1) * 64;
    const int wc   = (wid & 1) * 64;
    const int l15  = lane & 15;
    const int quad = lane >> 4;

    f32x4 acc[4][4];
    for (int i = 0; i < 4; i++)
        for (int j = 0; j < 4; j++) acc[i][j] = (f32x4)(0.0f);

    const bf16* Pb = P + (size_t)b * N_ * H_;

    for (int k0 = 0; k0 < N_; k0 += BK) {
        // A tile: straight bf16 copy (16 B per thread-chunk)
        for (int c = t; c < 512; c += 256) {
            int row = c >> 2, ch = c & 3;
            bf16x8 v = *(const bf16x8*)(Pb + (size_t)(i0 + row) * H_ + k0 + ch * 8);
            *(bf16x8*)&As[row * PITCH + ch * 8] = v;
        }
        // B tile: W[h0+n][k0+..] fp32 -> bf16, b128 writes
        for (int c = t; c < 512; c += 256) {
            int row = c >> 2, ch = c & 3;
            const float* s = W + (h0 + row) * H_ + k0 + ch * 8;
            const float4 v0 = *(const float4*)s;
            const float4 v1 = *(const float4*)(s + 4);
            bf16x8 p;
            p[0] = (bf16)v0.x; p[1] = (bf16)v0.y; p[2] = (bf16)v0.z; p[3] = (bf16)v0.w;
            p[4] = (bf16)v1.x; p[5] = (bf16)v1.y; p[6] = (bf16)v1.z; p[7] = (bf16)v1.w;
            *(bf16x8*)&Bs[row * PITCH + ch * 8] = p;
        }
        __syncthreads();
        bf16x8 af[4], bfr[4];
        for (int mt = 0; mt < 4; mt++)
            af[mt] = *(const bf16x8*)&As[(wr + mt * 16 + l15) * PITCH + quad * 8];
        for (int nt = 0; nt < 4; nt++)
            bfr[nt] = *(const bf16x8*)&Bs[(wc + nt * 16 + l15) * PITCH + quad * 8];
        for (int mt = 0; mt < 4; mt++)
            for (int nt = 0; nt < 4; nt++)
                acc[mt][nt] = __builtin_amdgcn_mfma_f32_16x16x32_bf16(af[mt], bfr[nt], acc[mt][nt], 0, 0, 0);
        __syncthreads();
    }

    float* ob = out + (size_t)b * N_ * H_;
    for (int mt = 0; mt < 4; mt++) {
        int row = i0 + wr + mt * 16 + quad * 4;
        for (int nt = 0; nt < 4; nt++) {
            int col = h0 + wc + nt * 16 + l15;
            float bv = bias[col];
            for (int r = 0; r < 4; r++) {
                float v = acc[mt][nt][r] + bv;
                float g = 0.5f * v * (1.0f + erff(v * 0.70710678118654752f));
                ob[(size_t)(row + r) * H_ + col] = g;
            }
        }
    }
}

// ---------------------------------------------------------------------------
// Quantum: one wave per batch element. 256 amplitudes = 64 lanes x 4 regs.
// idx = lane*4 + r; qubit w <-> bit (7-w). Gates on bits>=2 via shfl_xor,
// bits 1/0 in-register. No __syncthreads at all.
// ---------------------------------------------------------------------------
__global__ __launch_bounds__(64) void quantum_kernel(float* __restrict__ out,
                                                     const float* __restrict__ pre_w,
                                                     const float* __restrict__ pre_b,
                                                     const float* __restrict__ post_w,
                                                     const float* __restrict__ post_b,
                                                     const float* __restrict__ qw) {
    const int b = blockIdx.x;
    const int l = threadIdx.x;  // 0..63
    float* row0 = out + (size_t)b * N_ * H_;

    // target row (gelu output), 8 elems/lane
    float tg[8];
    #pragma unroll
    for (int j = 0; j < 8; j++) tg[j] = row0[l + 64 * j];

    // angles: tanh(tgt @ pre_w^T + pre_b) * pi
    float ang[NQ];
    #pragma unroll
    for (int q = 0; q < NQ; q++) {
        float s = 0.f;
        #pragma unroll
        for (int j = 0; j < 8; j++) s += tg[j] * pre_w[q * H_ + l + 64 * j];
        #pragma unroll
        for (int m = 32; m >= 1; m >>= 1) s += __shfl_xor(s, m, 64);
        ang[q] = tanhf(s + pre_b[q]) * 3.14159265358979323846f;
    }

    // initial RY product state (real): amp(idx) = prod_w (bit(7-w) ? sin : cos)
    float cw[NQ], sw[NQ];
    #pragma unroll
    for (int w = 0; w < NQ; w++) { cw[w] = cosf(0.5f * ang[w]); sw[w] = sinf(0.5f * ang[w]); }
    float re[4], im[4];
    #pragma unroll
    for (int r = 0; r < 4; r++) {
        int idx = l * 4 + r;
        float a = 1.f;
        #pragma unroll
        for (int w = 0; w < NQ; w++) a *= ((idx >> (7 - w)) & 1) ? sw[w] : cw[w];
        re[r] = a; im[r] = 0.f;
    }

    for (int lay = 0; lay < NL; lay++) {
        // ---- RX(qw[lay][w]) on each qubit: new = c*a - i*s*p ----
        // qubits 0..5 -> bits 7..2 -> lane xor masks 32,16,8,4,2,1
        #pragma unroll
        for (int w = 0; w < 6; w++) {
            float th = 0.5f * qw[lay * NQ + w];
            float c = cosf(th), s = sinf(th);
            int m = 1 << (5 - w);
            #pragma unroll
            for (int r = 0; r < 4; r++) {
                float pre_ = __shfl_xor(re[r], m, 64);
                float pim_ = __shfl_xor(im[r], m, 64);
                re[r] = c * re[r] + s * pim_;
                im[r] = c * im[r] - s * pre_;
            }
        }
        {   // qubit 6 -> bit 1: partner r^2
            float th = 0.5f * qw[lay * NQ + 6];
            float c = cosf(th), s = sinf(th);
            float or0 = re[0], or1 = re[1], or2 = re[2], or3 = re[3];
            float oi0 = im[0], oi1 = im[1], oi2 = im[2], oi3 = im[3];
            re[0] = c * or0 + s * oi2;  im[0] = c * oi0 - s * or2;
            re[1] = c * or1 + s * oi3;  im[1] = c * oi1 - s * or3;
            re[2] = c * or2 + s * oi0;  im[2] = c * oi2 - s * or0;
            re[3] = c * or3 + s * oi1;  im[3] = c * oi3 - s * or1;
        }
        {   // qubit 7 -> bit 0: partner r^1
            float th = 0.5f * qw[lay * NQ + 7];
            float c = cosf(th), s = sinf(th);
            float or0 = re[0], or1 = re[1], or2 = re[2], or3 = re[3];
            float oi0 = im[0], oi1 = im[1], oi2 = im[2], oi3 = im[3];
            re[0] = c * or0 + s * oi1;  im[0] = c * oi0 - s * or1;
            re[1] = c * or1 + s * oi0;  im[1] = c * oi1 - s * or0;
            re[2] = c * or2 + s * oi3;  im[2] = c * oi2 - s * or2 * 0.f - s * or3; // placeholder fixed below
            re[3] = c * or3 + s * oi2;  im[3] = c * oi3 - s * or2;
            im[2] = c * oi2 - s * or3;
        }
        // ---- CNOT ring: (c,t) = (w, w+1 mod 8); cb=7-c, tb=7-t ----
        // (0,1)..(4,5): both lane bits; target lane mask 1<<(tb-2), control lane bit (cb-2)
        #pragma unroll
        for (int w = 0; w < 5; w++) {
            int cb = 7 - w;        // 7..3
            int tb = 6 - w;        // 6..2
            int tm = 1 << (tb - 2);
            bool ctl = (l >> (cb - 2)) & 1;
            #pragma unroll
            for (int r = 0; r < 4; r++) {
                float pre_ = __shfl_xor(re[r], tm, 64);
                float pim_ = __shfl_xor(im[r], tm, 64);
                re[r] = ctl ? pre_ : re[r];
                im[r] = ctl ? pim_ : im[r];
            }
        }
        {   // (5,6): cb=2 (lane bit 0), tb=1 (r^2)
            bool ctl = l & 1;
            float t0 = re[0], t1 = re[1], t2 = re[2], t3 = re[3];
            float u0 = im[0], u1 = im[1], u2 = im[2], u3 = im[3];
            re[0] = ctl ? t2 : t0;  re[1] = ctl ? t3 : t1;
            re[2] = ctl ? t0 : t2;  re[3] = ctl ? t1 : t3;
            im[0] = ctl ? u2 : u0;  im[1] = ctl ? u3 : u1;
            im[2] = ctl ? u0 : u2;  im[3] = ctl ? u1 : u3;
        }
        {   // (6,7): cb=1 (r bit1), tb=0 (r^1): swap r=2<->3
            float t2 = re[2], t3 = re[3], u2 = im[2], u3 = im[3];
            re[2] = t3; re[3] = t2; im[2] = u3; im[3] = u2;
        }
        {   // (7,0): cb=0 (r bit0), tb=7 (lane mask 32): odd r take partner
            #pragma unroll
            for (int r = 0; r < 4; r++) {
                float pre_ = __shfl_xor(re[r], 32, 64);
                float pim_ = __shfl_xor(im[r], 32, 64);
                if (r & 1) { re[r] = pre_; im[r] = pim_; }
            }
        }
    }

    // <Z_q> and output row
    float pr[4];
    #pragma unroll
    for (int r = 0; r < 4; r++) pr[r] = re[r] * re[r] + im[r] * im[r];
    float z[NQ];
    #pragma unroll
    for (int q = 0; q < NQ; q++) {
        int bit = 7 - q;
        float s = 0.f;
        #pragma unroll
        for (int r = 0; r < 4; r++) {
            int idx = l * 4 + r;
            s += ((idx >> bit) & 1) ? -pr[r] : pr[r];
        }
        #pragma unroll
        for (int m = 32; m >= 1; m >>= 1) s += __shfl_xor(s, m, 64);
        z[q] = s;
    }

    #pragma unroll
    for (int j = 0; j < 8; j++) {
        int h = l + 64 * j;
        float v = post_b[h];
        #pragma unroll
        for (int q = 0; q < NQ; q++) v += z[q] * post_w[h * NQ + q];
        row0[h] = v;
    }
}

// ---------------------------------------------------------------------------
extern "C" void kernel_launch(void* const* d_in, const int* in_sizes, int n_in,
                              void* d_out, int out_size, void* d_ws, size_t ws_size,
                              hipStream_t stream) {
    const float* x        = (const float*)d_in[0];
    const float* norm_adj = (const float*)d_in[1];
    const float* W_gcn_w  = (const float*)d_in[2];
    const float* W_gcn_b  = (const float*)d_in[3];
    const float* pre_w    = (const float*)d_in[4];
    const float* pre_b    = (const float*)d_in[5];
    const float* post_w   = (const float*)d_in[6];
    const float* post_b   = (const float*)d_in[7];
    const float* q_w      = (const float*)d_in[8];
    float* out = (float*)d_out;
    bf16* P = (bf16*)d_ws;   // 32 MiB

    dim3 grid(16, B_);
    gemm1_kernel<<<grid, 256, 0, stream>>>(norm_adj, x, P);
    gemm2_kernel<<<grid, 256, 0, stream>>>(P, W_gcn_w, W_gcn_b, out);
    quantum_kernel<<<B_, 64, 0, stream>>>(out, pre_w, pre_b, post_w, post_b, q_w);
}

// Round 3
// 254.920 us; speedup vs baseline: 1.3606x; 1.0362x over previous
//
#include <hip/hip_runtime.h>
#include <hip/hip_bf16.h>
#include <math.h>

#define B_  64
#define D_  512
#define NQ  8
#define NL  4

typedef __bf16 bf16;
typedef float  f32x4  __attribute__((ext_vector_type(4)));
typedef bf16   bf16x8 __attribute__((ext_vector_type(8)));

#define PITCH 40   // A-tile LDS pitch (bf16): 80 B rows -> (5*row+quad)%8 start pos, 2-way free

__device__ __forceinline__ void async_load16(const bf16* g, bf16* l) {
    __builtin_amdgcn_global_load_lds(
        (const __attribute__((address_space(1))) void*)g,
        (__attribute__((address_space(3))) void*)l, 16, 0, 0);
}

// ---------------------------------------------------------------------------
// fp32 -> bf16 bulk convert (8 elems / thread)
// ---------------------------------------------------------------------------
__global__ __launch_bounds__(256) void convert_kernel(const float* __restrict__ src,
                                                      bf16* __restrict__ dst, int n8) {
    int i = blockIdx.x * 256 + threadIdx.x;
    if (i < n8) {
        const float4 v0 = *(const float4*)(src + (size_t)i * 8);
        const float4 v1 = *(const float4*)(src + (size_t)i * 8 + 4);
        bf16x8 p;
        p[0] = (bf16)v0.x; p[1] = (bf16)v0.y; p[2] = (bf16)v0.z; p[3] = (bf16)v0.w;
        p[4] = (bf16)v1.x; p[5] = (bf16)v1.y; p[6] = (bf16)v1.z; p[7] = (bf16)v1.w;
        *(bf16x8*)(dst + (size_t)i * 8) = p;
    }
}

// ---------------------------------------------------------------------------
// NT GEMM: C[b][m][n] = (gelu?)( sum_k A[m][k] * Bv[b][n][k] (+ bias[n]) )
// A: 512x512 fp32 (shared across batch, L2-hot) -> VALU-convert staged.
// Bv: per-batch bf16, k-contiguous -> global_load_lds (16B) w/ XOR swizzle.
// GELU=0: C stored bf16. GELU=1: C stored fp32 with bias+exact-gelu.
// ---------------------------------------------------------------------------
template <int GELU>
__global__ __launch_bounds__(256) void gemm_nt(const float* __restrict__ A,
                                               const bf16* __restrict__ Bv,
                                               const float* __restrict__ bias,
                                               void* __restrict__ Cout) {
    __shared__ bf16 As[128 * PITCH];   // [m][k], padded pitch
    __shared__ bf16 Bs[128 * 32];      // [n][k], no pad (DMA), chunk-XOR-swizzled
    const int b    = blockIdx.y;
    const int tile = blockIdx.x;
    const int m0   = (tile >> 2) * 128;
    const int n0   = (tile & 3) * 128;
    const int t    = threadIdx.x;
    const int lane = t & 63;
    const int w    = t >> 6;
    const int wr   = (w >> 1) * 64;
    const int wc   = (w & 1) * 64;
    const int l15  = lane & 15;
    const int quad = lane >> 4;

    f32x4 acc[4][4];
    for (int i = 0; i < 4; i++)
        for (int j = 0; j < 4; j++) acc[i][j] = (f32x4)(0.0f);

    const bf16* Bb = Bv + (size_t)b * D_ * D_;

    for (int k0 = 0; k0 < D_; k0 += 32) {
        // ---- A stage: fp32 load + convert + ds_write_b128 (512 chunks of 8)
        for (int c = t; c < 512; c += 256) {
            int row = c >> 2, ch = c & 3;
            const float* s = A + (size_t)(m0 + row) * D_ + k0 + ch * 8;
            const float4 v0 = *(const float4*)s;
            const float4 v1 = *(const float4*)(s + 4);
            bf16x8 p;
            p[0] = (bf16)v0.x; p[1] = (bf16)v0.y; p[2] = (bf16)v0.z; p[3] = (bf16)v0.w;
            p[4] = (bf16)v1.x; p[5] = (bf16)v1.y; p[6] = (bf16)v1.z; p[7] = (bf16)v1.w;
            *(bf16x8*)&As[row * PITCH + ch * 8] = p;
        }
        // ---- B stage: DMA direct-to-LDS, 8 issues of 1 KiB (2 per wave).
        // lane i covers row rbase+(i>>2), LDS slot (i&3); source chunk is
        // slot ^ ((row>>1)&3) so LDS slot s holds chunk s^((row>>1)&3).
        {
            int rl = lane >> 2;                       // row within 16-row issue
            int kchunk = (lane & 3) ^ ((lane >> 3) & 3);
            #pragma unroll
            for (int j = 0; j < 2; j++) {
                int rbase = w * 32 + j * 16;
                const bf16* g = Bb + (size_t)(n0 + rbase + rl) * D_ + k0 + kchunk * 8;
                async_load16(g, &Bs[rbase * 32]);
            }
        }
        __syncthreads();
        bf16x8 af[4], bfr[4];
        #pragma unroll
        for (int mt = 0; mt < 4; mt++)
            af[mt] = *(const bf16x8*)&As[(wr + mt * 16 + l15) * PITCH + quad * 8];
        #pragma unroll
        for (int nt = 0; nt < 4; nt++) {
            int row = wc + nt * 16 + l15;
            int kx  = quad ^ ((l15 >> 1) & 3);        // undo staging swizzle
            bfr[nt] = *(const bf16x8*)&Bs[row * 32 + kx * 8];
        }
        #pragma unroll
        for (int mt = 0; mt < 4; mt++)
            #pragma unroll
            for (int nt = 0; nt < 4; nt++)
                acc[mt][nt] = __builtin_amdgcn_mfma_f32_16x16x32_bf16(af[mt], bfr[nt], acc[mt][nt], 0, 0, 0);
        __syncthreads();
    }

    if (GELU == 0) {
        bf16* Cb = (bf16*)Cout + (size_t)b * D_ * D_;
        for (int mt = 0; mt < 4; mt++) {
            int row = m0 + wr + mt * 16 + quad * 4;
            for (int nt = 0; nt < 4; nt++) {
                int col = n0 + wc + nt * 16 + l15;
                for (int r = 0; r < 4; r++)
                    Cb[(size_t)(row + r) * D_ + col] = (bf16)acc[mt][nt][r];
            }
        }
    } else {
        float* Cb = (float*)Cout + (size_t)b * D_ * D_;
        for (int mt = 0; mt < 4; mt++) {
            int row = m0 + wr + mt * 16 + quad * 4;
            for (int nt = 0; nt < 4; nt++) {
                int col = n0 + wc + nt * 16 + l15;
                float bv = bias[col];
                for (int r = 0; r < 4; r++) {
                    float v = acc[mt][nt][r] + bv;
                    Cb[(size_t)(row + r) * D_ + col] = 0.5f * v * (1.0f + erff(v * 0.70710678118654752f));
                }
            }
        }
    }
}

// ---------------------------------------------------------------------------
// Quantum: one wave per batch element (unchanged from R2, validated).
// ---------------------------------------------------------------------------
__global__ __launch_bounds__(64) void quantum_kernel(float* __restrict__ out,
                                                     const float* __restrict__ pre_w,
                                                     const float* __restrict__ pre_b,
                                                     const float* __restrict__ post_w,
                                                     const float* __restrict__ post_b,
                                                     const float* __restrict__ qw) {
    const int b = blockIdx.x;
    const int l = threadIdx.x;
    float* row0 = out + (size_t)b * D_ * D_;

    float tg[8];
    #pragma unroll
    for (int j = 0; j < 8; j++) tg[j] = row0[l + 64 * j];

    float ang[NQ];
    #pragma unroll
    for (int q = 0; q < NQ; q++) {
        float s = 0.f;
        #pragma unroll
        for (int j = 0; j < 8; j++) s += tg[j] * pre_w[q * D_ + l + 64 * j];
        #pragma unroll
        for (int m = 32; m >= 1; m >>= 1) s += __shfl_xor(s, m, 64);
        ang[q] = tanhf(s + pre_b[q]) * 3.14159265358979323846f;
    }

    float cw[NQ], sw[NQ];
    #pragma unroll
    for (int w = 0; w < NQ; w++) { cw[w] = cosf(0.5f * ang[w]); sw[w] = sinf(0.5f * ang[w]); }
    float re[4], im[4];
    #pragma unroll
    for (int r = 0; r < 4; r++) {
        int idx = l * 4 + r;
        float a = 1.f;
        #pragma unroll
        for (int w = 0; w < NQ; w++) a *= ((idx >> (7 - w)) & 1) ? sw[w] : cw[w];
        re[r] = a; im[r] = 0.f;
    }

    for (int lay = 0; lay < NL; lay++) {
        #pragma unroll
        for (int w = 0; w < 6; w++) {
            float th = 0.5f * qw[lay * NQ + w];
            float c = cosf(th), s = sinf(th);
            int m = 1 << (5 - w);
            #pragma unroll
            for (int r = 0; r < 4; r++) {
                float pre_ = __shfl_xor(re[r], m, 64);
                float pim_ = __shfl_xor(im[r], m, 64);
                re[r] = c * re[r] + s * pim_;
                im[r] = c * im[r] - s * pre_;
            }
        }
        {   // qubit 6 (bit 1): partner r^2
            float th = 0.5f * qw[lay * NQ + 6];
            float c = cosf(th), s = sinf(th);
            float or0 = re[0], or1 = re[1], or2 = re[2], or3 = re[3];
            float oi0 = im[0], oi1 = im[1], oi2 = im[2], oi3 = im[3];
            re[0] = c * or0 + s * oi2;  im[0] = c * oi0 - s * or2;
            re[1] = c * or1 + s * oi3;  im[1] = c * oi1 - s * or3;
            re[2] = c * or2 + s * oi0;  im[2] = c * oi2 - s * or0;
            re[3] = c * or3 + s * oi1;  im[3] = c * oi3 - s * or1;
        }
        {   // qubit 7 (bit 0): partner r^1
            float th = 0.5f * qw[lay * NQ + 7];
            float c = cosf(th), s = sinf(th);
            float or0 = re[0], or1 = re[1], or2 = re[2], or3 = re[3];
            float oi0 = im[0], oi1 = im[1], oi2 = im[2], oi3 = im[3];
            re[0] = c * or0 + s * oi1;  im[0] = c * oi0 - s * or1;
            re[1] = c * or1 + s * oi0;  im[1] = c * oi1 - s * or0;
            re[2] = c * or2 + s * oi3;  im[2] = c * oi2 - s * or3;
            re[3] = c * or3 + s * oi2;  im[3] = c * oi3 - s * or2;
        }
        #pragma unroll
        for (int w = 0; w < 5; w++) {
            int cb = 7 - w, tb = 6 - w;
            int tm = 1 << (tb - 2);
            bool ctl = (l >> (cb - 2)) & 1;
            #pragma unroll
            for (int r = 0; r < 4; r++) {
                float pre_ = __shfl_xor(re[r], tm, 64);
                float pim_ = __shfl_xor(im[r], tm, 64);
                re[r] = ctl ? pre_ : re[r];
                im[r] = ctl ? pim_ : im[r];
            }
        }
        {   // (5,6)
            bool ctl = l & 1;
            float t0 = re[0], t1 = re[1], t2 = re[2], t3 = re[3];
            float u0 = im[0], u1 = im[1], u2 = im[2], u3 = im[3];
            re[0] = ctl ? t2 : t0;  re[1] = ctl ? t3 : t1;
            re[2] = ctl ? t0 : t2;  re[3] = ctl ? t1 : t3;
            im[0] = ctl ? u2 : u0;  im[1] = ctl ? u3 : u1;
            im[2] = ctl ? u0 : u2;  im[3] = ctl ? u1 : u3;
        }
        {   // (6,7)
            float t2 = re[2], t3 = re[3], u2 = im[2], u3 = im[3];
            re[2] = t3; re[3] = t2; im[2] = u3; im[3] = u2;
        }
        {   // (7,0)
            #pragma unroll
            for (int r = 0; r < 4; r++) {
                float pre_ = __shfl_xor(re[r], 32, 64);
                float pim_ = __shfl_xor(im[r], 32, 64);
                if (r & 1) { re[r] = pre_; im[r] = pim_; }
            }
        }
    }

    float pr[4];
    #pragma unroll
    for (int r = 0; r < 4; r++) pr[r] = re[r] * re[r] + im[r] * im[r];
    float z[NQ];
    #pragma unroll
    for (int q = 0; q < NQ; q++) {
        int bit = 7 - q;
        float s = 0.f;
        #pragma unroll
        for (int r = 0; r < 4; r++) {
            int idx = l * 4 + r;
            s += ((idx >> bit) & 1) ? -pr[r] : pr[r];
        }
        #pragma unroll
        for (int m = 32; m >= 1; m >>= 1) s += __shfl_xor(s, m, 64);
        z[q] = s;
    }

    #pragma unroll
    for (int j = 0; j < 8; j++) {
        int h = l + 64 * j;
        float v = post_b[h];
        #pragma unroll
        for (int q = 0; q < NQ; q++) v += z[q] * post_w[h * NQ + q];
        row0[h] = v;
    }
}

// ---------------------------------------------------------------------------
extern "C" void kernel_launch(void* const* d_in, const int* in_sizes, int n_in,
                              void* d_out, int out_size, void* d_ws, size_t ws_size,
                              hipStream_t stream) {
    const float* x        = (const float*)d_in[0];
    const float* norm_adj = (const float*)d_in[1];
    const float* W_gcn_w  = (const float*)d_in[2];
    const float* W_gcn_b  = (const float*)d_in[3];
    const float* pre_w    = (const float*)d_in[4];
    const float* pre_b    = (const float*)d_in[5];
    const float* post_w   = (const float*)d_in[6];
    const float* post_b   = (const float*)d_in[7];
    const float* q_w      = (const float*)d_in[8];
    float* out = (float*)d_out;

    // Scratch plan: xbf (32 MiB) lives in d_out's 64 MiB (dead until gemm2
    // overwrites it, stream-ordered). Yt (32 MiB) in d_ws (known >= 32 MiB).
    bf16* xbf = (bf16*)d_out;
    bf16* Yt  = (bf16*)d_ws;

    convert_kernel<<<(B_ * D_ * D_ / 8 + 255) / 256, 256, 0, stream>>>(x, xbf, B_ * D_ * D_ / 8);

    dim3 grid(16, B_);
    // Yt[b][g][j] = sum_h W[g][h] * x[b][j][h]
    gemm_nt<0><<<grid, 256, 0, stream>>>(W_gcn_w, xbf, nullptr, (void*)Yt);
    // out[b][i][g] = gelu( sum_j adj[i][j] * Yt[b][g][j] + bias[g] )
    gemm_nt<1><<<grid, 256, 0, stream>>>(norm_adj, Yt, W_gcn_b, (void*)out);

    quantum_kernel<<<B_, 64, 0, stream>>>(out, pre_w, pre_b, post_w, post_b, q_w);
}

// Round 4
// 204.541 us; speedup vs baseline: 1.6957x; 1.2463x over previous
//
#include <hip/hip_runtime.h>
#include <hip/hip_bf16.h>
#include <math.h>

#define B_  64
#define D_  512
#define NQ  8
#define NL  4

typedef __bf16 bf16;
typedef float  f32x4  __attribute__((ext_vector_type(4)));
typedef bf16   bf16x8 __attribute__((ext_vector_type(8)));

__device__ __forceinline__ void async_load16(const bf16* g, bf16* l) {
    __builtin_amdgcn_global_load_lds(
        (const __attribute__((address_space(1))) void*)g,
        (__attribute__((address_space(3))) void*)l, 16, 0, 0);
}

// ---------------------------------------------------------------------------
// fp32 -> bf16 bulk convert (8 elems / thread)
// ---------------------------------------------------------------------------
__global__ __launch_bounds__(256) void convert_kernel(const float* __restrict__ src,
                                                      bf16* __restrict__ dst, int n8) {
    int i = blockIdx.x * 256 + threadIdx.x;
    if (i < n8) {
        const float4 v0 = *(const float4*)(src + (size_t)i * 8);
        const float4 v1 = *(const float4*)(src + (size_t)i * 8 + 4);
        bf16x8 p;
        p[0] = (bf16)v0.x; p[1] = (bf16)v0.y; p[2] = (bf16)v0.z; p[3] = (bf16)v0.w;
        p[4] = (bf16)v1.x; p[5] = (bf16)v1.y; p[6] = (bf16)v1.z; p[7] = (bf16)v1.w;
        *(bf16x8*)(dst + (size_t)i * 8) = p;
    }
}

// ---------------------------------------------------------------------------
// Full-DMA NT GEMM: C[b][m][n] = (gelu?)( sum_k A[m][k]*Bv[b][n][k] (+bias) )
// Both operands bf16 k-contiguous, staged via global_load_lds (16B) with
// chunk-XOR swizzle: LDS slot s of row r holds global chunk s^(r&7).
// BK=64: 8 K-steps, 2 MFMA sub-steps per stage.
// ---------------------------------------------------------------------------
template <int GELU>
__global__ __launch_bounds__(256) void gemm_nt_dma(const bf16* __restrict__ A,
                                                   const bf16* __restrict__ Bv,
                                                   const float* __restrict__ bias,
                                                   void* __restrict__ Cout) {
    __shared__ bf16 As[128 * 64];   // [row][k], 128 B rows, XOR-swizzled
    __shared__ bf16 Bs[128 * 64];
    const int b    = blockIdx.y;
    const int tile = blockIdx.x;
    const int m0   = (tile >> 2) * 128;
    const int n0   = (tile & 3) * 128;
    const int t    = threadIdx.x;
    const int lane = t & 63;
    const int w    = t >> 6;
    const int wr   = (w >> 1) * 64;
    const int wc   = (w & 1) * 64;
    const int l15  = lane & 15;
    const int quad = lane >> 4;

    f32x4 acc[4][4];
    for (int i = 0; i < 4; i++)
        for (int j = 0; j < 4; j++) acc[i][j] = (f32x4)(0.0f);

    const bf16* Bb = Bv + (size_t)b * D_ * D_;

    // staging geometry: one issue = 64 lanes x 16B = 8 rows of 128 B.
    const int rl = lane >> 3;              // row within issue (0..7)
    const int ck = (lane & 7) ^ rl;        // global chunk for this lane's slot

    for (int k0 = 0; k0 < D_; k0 += 64) {
        #pragma unroll
        for (int j = 0; j < 4; j++) {
            int rbase = w * 32 + j * 8;
            async_load16(A  + (size_t)(m0 + rbase + rl) * D_ + k0 + ck * 8, &As[rbase * 64]);
            async_load16(Bb + (size_t)(n0 + rbase + rl) * D_ + k0 + ck * 8, &Bs[rbase * 64]);
        }
        __syncthreads();
        #pragma unroll
        for (int kk = 0; kk < 2; kk++) {
            bf16x8 af[4], bfr[4];
            #pragma unroll
            for (int mt = 0; mt < 4; mt++) {
                int row = wr + mt * 16 + l15;
                int s   = (kk * 4 + quad) ^ (l15 & 7);
                af[mt] = *(const bf16x8*)&As[row * 64 + s * 8];
            }
            #pragma unroll
            for (int nt = 0; nt < 4; nt++) {
                int row = wc + nt * 16 + l15;
                int s   = (kk * 4 + quad) ^ (l15 & 7);
                bfr[nt] = *(const bf16x8*)&Bs[row * 64 + s * 8];
            }
            #pragma unroll
            for (int mt = 0; mt < 4; mt++)
                #pragma unroll
                for (int nt = 0; nt < 4; nt++)
                    acc[mt][nt] = __builtin_amdgcn_mfma_f32_16x16x32_bf16(af[mt], bfr[nt], acc[mt][nt], 0, 0, 0);
        }
        __syncthreads();
    }

    if (GELU == 0) {
        bf16* Cb = (bf16*)Cout + (size_t)b * D_ * D_;
        for (int mt = 0; mt < 4; mt++) {
            int row = m0 + wr + mt * 16 + quad * 4;
            for (int nt = 0; nt < 4; nt++) {
                int col = n0 + wc + nt * 16 + l15;
                for (int r = 0; r < 4; r++)
                    Cb[(size_t)(row + r) * D_ + col] = (bf16)acc[mt][nt][r];
            }
        }
    } else {
        float* Cb = (float*)Cout + (size_t)b * D_ * D_;
        for (int mt = 0; mt < 4; mt++) {
            int row = m0 + wr + mt * 16 + quad * 4;
            for (int nt = 0; nt < 4; nt++) {
                int col = n0 + wc + nt * 16 + l15;
                float bv = bias[col];
                for (int r = 0; r < 4; r++) {
                    float v = acc[mt][nt][r] + bv;
                    Cb[(size_t)(row + r) * D_ + col] = 0.5f * v * (1.0f + erff(v * 0.70710678118654752f));
                }
            }
        }
    }
}

// ---------------------------------------------------------------------------
// Legacy R3 GEMM (fallback if ws too small for bf16 A copies)
// ---------------------------------------------------------------------------
#define PITCH 40
template <int GELU>
__global__ __launch_bounds__(256) void gemm_nt_legacy(const float* __restrict__ A,
                                                      const bf16* __restrict__ Bv,
                                                      const float* __restrict__ bias,
                                                      void* __restrict__ Cout) {
    __shared__ bf16 As[128 * PITCH];
    __shared__ bf16 Bs[128 * 32];
    const int b    = blockIdx.y;
    const int tile = blockIdx.x;
    const int m0   = (tile >> 2) * 128;
    const int n0   = (tile & 3) * 128;
    const int t    = threadIdx.x;
    const int lane = t & 63;
    const int w    = t >> 6;
    const int wr   = (w >> 1) * 64;
    const int wc   = (w & 1) * 64;
    const int l15  = lane & 15;
    const int quad = lane >> 4;

    f32x4 acc[4][4];
    for (int i = 0; i < 4; i++)
        for (int j = 0; j < 4; j++) acc[i][j] = (f32x4)(0.0f);

    const bf16* Bb = Bv + (size_t)b * D_ * D_;

    for (int k0 = 0; k0 < D_; k0 += 32) {
        for (int c = t; c < 512; c += 256) {
            int row = c >> 2, ch = c & 3;
            const float* s = A + (size_t)(m0 + row) * D_ + k0 + ch * 8;
            const float4 v0 = *(const float4*)s;
            const float4 v1 = *(const float4*)(s + 4);
            bf16x8 p;
            p[0] = (bf16)v0.x; p[1] = (bf16)v0.y; p[2] = (bf16)v0.z; p[3] = (bf16)v0.w;
            p[4] = (bf16)v1.x; p[5] = (bf16)v1.y; p[6] = (bf16)v1.z; p[7] = (bf16)v1.w;
            *(bf16x8*)&As[row * PITCH + ch * 8] = p;
        }
        {
            int rl = lane >> 2;
            int kchunk = (lane & 3) ^ ((lane >> 3) & 3);
            #pragma unroll
            for (int j = 0; j < 2; j++) {
                int rbase = w * 32 + j * 16;
                async_load16(Bb + (size_t)(n0 + rbase + rl) * D_ + k0 + kchunk * 8, &Bs[rbase * 32]);
            }
        }
        __syncthreads();
        bf16x8 af[4], bfr[4];
        #pragma unroll
        for (int mt = 0; mt < 4; mt++)
            af[mt] = *(const bf16x8*)&As[(wr + mt * 16 + l15) * PITCH + quad * 8];
        #pragma unroll
        for (int nt = 0; nt < 4; nt++) {
            int row = wc + nt * 16 + l15;
            int kx  = quad ^ ((l15 >> 1) & 3);
            bfr[nt] = *(const bf16x8*)&Bs[row * 32 + kx * 8];
        }
        #pragma unroll
        for (int mt = 0; mt < 4; mt++)
            #pragma unroll
            for (int nt = 0; nt < 4; nt++)
                acc[mt][nt] = __builtin_amdgcn_mfma_f32_16x16x32_bf16(af[mt], bfr[nt], acc[mt][nt], 0, 0, 0);
        __syncthreads();
    }

    if (GELU == 0) {
        bf16* Cb = (bf16*)Cout + (size_t)b * D_ * D_;
        for (int mt = 0; mt < 4; mt++) {
            int row = m0 + wr + mt * 16 + quad * 4;
            for (int nt = 0; nt < 4; nt++) {
                int col = n0 + wc + nt * 16 + l15;
                for (int r = 0; r < 4; r++)
                    Cb[(size_t)(row + r) * D_ + col] = (bf16)acc[mt][nt][r];
            }
        }
    } else {
        float* Cb = (float*)Cout + (size_t)b * D_ * D_;
        for (int mt = 0; mt < 4; mt++) {
            int row = m0 + wr + mt * 16 + quad * 4;
            for (int nt = 0; nt < 4; nt++) {
                int col = n0 + wc + nt * 16 + l15;
                float bv = bias[col];
                for (int r = 0; r < 4; r++) {
                    float v = acc[mt][nt][r] + bv;
                    Cb[(size_t)(row + r) * D_ + col] = 0.5f * v * (1.0f + erff(v * 0.70710678118654752f));
                }
            }
        }
    }
}

// ---------------------------------------------------------------------------
// Quantum: one wave per batch element (validated in R2/R3).
// ---------------------------------------------------------------------------
__global__ __launch_bounds__(64) void quantum_kernel(float* __restrict__ out,
                                                     const float* __restrict__ pre_w,
                                                     const float* __restrict__ pre_b,
                                                     const float* __restrict__ post_w,
                                                     const float* __restrict__ post_b,
                                                     const float* __restrict__ qw) {
    const int b = blockIdx.x;
    const int l = threadIdx.x;
    float* row0 = out + (size_t)b * D_ * D_;

    float tg[8];
    #pragma unroll
    for (int j = 0; j < 8; j++) tg[j] = row0[l + 64 * j];

    float ang[NQ];
    #pragma unroll
    for (int q = 0; q < NQ; q++) {
        float s = 0.f;
        #pragma unroll
        for (int j = 0; j < 8; j++) s += tg[j] * pre_w[q * D_ + l + 64 * j];
        #pragma unroll
        for (int m = 32; m >= 1; m >>= 1) s += __shfl_xor(s, m, 64);
        ang[q] = tanhf(s + pre_b[q]) * 3.14159265358979323846f;
    }

    float cw[NQ], sw[NQ];
    #pragma unroll
    for (int w = 0; w < NQ; w++) { cw[w] = cosf(0.5f * ang[w]); sw[w] = sinf(0.5f * ang[w]); }
    float re[4], im[4];
    #pragma unroll
    for (int r = 0; r < 4; r++) {
        int idx = l * 4 + r;
        float a = 1.f;
        #pragma unroll
        for (int w = 0; w < NQ; w++) a *= ((idx >> (7 - w)) & 1) ? sw[w] : cw[w];
        re[r] = a; im[r] = 0.f;
    }

    for (int lay = 0; lay < NL; lay++) {
        #pragma unroll
        for (int w = 0; w < 6; w++) {
            float th = 0.5f * qw[lay * NQ + w];
            float c = cosf(th), s = sinf(th);
            int m = 1 << (5 - w);
            #pragma unroll
            for (int r = 0; r < 4; r++) {
                float pre_ = __shfl_xor(re[r], m, 64);
                float pim_ = __shfl_xor(im[r], m, 64);
                re[r] = c * re[r] + s * pim_;
                im[r] = c * im[r] - s * pre_;
            }
        }
        {   // qubit 6 (bit 1): partner r^2
            float th = 0.5f * qw[lay * NQ + 6];
            float c = cosf(th), s = sinf(th);
            float or0 = re[0], or1 = re[1], or2 = re[2], or3 = re[3];
            float oi0 = im[0], oi1 = im[1], oi2 = im[2], oi3 = im[3];
            re[0] = c * or0 + s * oi2;  im[0] = c * oi0 - s * or2;
            re[1] = c * or1 + s * oi3;  im[1] = c * oi1 - s * or3;
            re[2] = c * or2 + s * oi0;  im[2] = c * oi2 - s * or0;
            re[3] = c * or3 + s * oi1;  im[3] = c * oi3 - s * or1;
        }
        {   // qubit 7 (bit 0): partner r^1
            float th = 0.5f * qw[lay * NQ + 7];
            float c = cosf(th), s = sinf(th);
            float or0 = re[0], or1 = re[1], or2 = re[2], or3 = re[3];
            float oi0 = im[0], oi1 = im[1], oi2 = im[2], oi3 = im[3];
            re[0] = c * or0 + s * oi1;  im[0] = c * oi0 - s * or1;
            re[1] = c * or1 + s * oi0;  im[1] = c * oi1 - s * or0;
            re[2] = c * or2 + s * oi3;  im[2] = c * oi2 - s * or3;
            re[3] = c * or3 + s * oi2;  im[3] = c * oi3 - s * or2;
        }
        #pragma unroll
        for (int w = 0; w < 5; w++) {
            int cb = 7 - w, tb = 6 - w;
            int tm = 1 << (tb - 2);
            bool ctl = (l >> (cb - 2)) & 1;
            #pragma unroll
            for (int r = 0; r < 4; r++) {
                float pre_ = __shfl_xor(re[r], tm, 64);
                float pim_ = __shfl_xor(im[r], tm, 64);
                re[r] = ctl ? pre_ : re[r];
                im[r] = ctl ? pim_ : im[r];
            }
        }
        {   // (5,6)
            bool ctl = l & 1;
            float t0 = re[0], t1 = re[1], t2 = re[2], t3 = re[3];
            float u0 = im[0], u1 = im[1], u2 = im[2], u3 = im[3];
            re[0] = ctl ? t2 : t0;  re[1] = ctl ? t3 : t1;
            re[2] = ctl ? t0 : t2;  re[3] = ctl ? t1 : t3;
            im[0] = ctl ? u2 : u0;  im[1] = ctl ? u3 : u1;
            im[2] = ctl ? u0 : u2;  im[3] = ctl ? u1 : u3;
        }
        {   // (6,7)
            float t2 = re[2], t3 = re[3], u2 = im[2], u3 = im[3];
            re[2] = t3; re[3] = t2; im[2] = u3; im[3] = u2;
        }
        {   // (7,0)
            #pragma unroll
            for (int r = 0; r < 4; r++) {
                float pre_ = __shfl_xor(re[r], 32, 64);
                float pim_ = __shfl_xor(im[r], 32, 64);
                if (r & 1) { re[r] = pre_; im[r] = pim_; }
            }
        }
    }

    float pr[4];
    #pragma unroll
    for (int r = 0; r < 4; r++) pr[r] = re[r] * re[r] + im[r] * im[r];
    float z[NQ];
    #pragma unroll
    for (int q = 0; q < NQ; q++) {
        int bit = 7 - q;
        float s = 0.f;
        #pragma unroll
        for (int r = 0; r < 4; r++) {
            int idx = l * 4 + r;
            s += ((idx >> bit) & 1) ? -pr[r] : pr[r];
        }
        #pragma unroll
        for (int m = 32; m >= 1; m >>= 1) s += __shfl_xor(s, m, 64);
        z[q] = s;
    }

    #pragma unroll
    for (int j = 0; j < 8; j++) {
        int h = l + 64 * j;
        float v = post_b[h];
        #pragma unroll
        for (int q = 0; q < NQ; q++) v += z[q] * post_w[h * NQ + q];
        row0[h] = v;
    }
}

// ---------------------------------------------------------------------------
extern "C" void kernel_launch(void* const* d_in, const int* in_sizes, int n_in,
                              void* d_out, int out_size, void* d_ws, size_t ws_size,
                              hipStream_t stream) {
    const float* x        = (const float*)d_in[0];
    const float* norm_adj = (const float*)d_in[1];
    const float* W_gcn_w  = (const float*)d_in[2];
    const float* W_gcn_b  = (const float*)d_in[3];
    const float* pre_w    = (const float*)d_in[4];
    const float* pre_b    = (const float*)d_in[5];
    const float* post_w   = (const float*)d_in[6];
    const float* post_b   = (const float*)d_in[7];
    const float* q_w      = (const float*)d_in[8];
    float* out = (float*)d_out;

    bf16* xbf = (bf16*)d_out;            // first 32 MiB of d_out: dead until gemm2 writes
    bf16* Yt  = (bf16*)d_ws;             // 32 MiB

    const int n8_x = B_ * D_ * D_ / 8;
    const int n8_m = D_ * D_ / 8;
    convert_kernel<<<(n8_x + 255) / 256, 256, 0, stream>>>(x, xbf, n8_x);

    dim3 grid(16, B_);
    const size_t MB32 = (size_t)32 * 1024 * 1024;
    if (ws_size >= MB32 + 2 * 1024 * 1024) {
        bf16* Wbf   = (bf16*)((char*)d_ws + MB32);
        bf16* adjbf = Wbf + D_ * D_;
        convert_kernel<<<(n8_m + 255) / 256, 256, 0, stream>>>(W_gcn_w, Wbf, n8_m);
        convert_kernel<<<(n8_m + 255) / 256, 256, 0, stream>>>(norm_adj, adjbf, n8_m);
        // Yt[b][g][j] = sum_h W[g][h] * x[b][j][h]
        gemm_nt_dma<0><<<grid, 256, 0, stream>>>(Wbf, xbf, nullptr, (void*)Yt);
        // out[b][i][g] = gelu( sum_j adj[i][j] * Yt[b][g][j] + bias[g] )
        gemm_nt_dma<1><<<grid, 256, 0, stream>>>(adjbf, Yt, W_gcn_b, (void*)out);
    } else {
        gemm_nt_legacy<0><<<grid, 256, 0, stream>>>(W_gcn_w, xbf, nullptr, (void*)Yt);
        gemm_nt_legacy<1><<<grid, 256, 0, stream>>>(norm_adj, Yt, W_gcn_b, (void*)out);
    }

    quantum_kernel<<<B_, 64, 0, stream>>>(out, pre_w, pre_b, post_w, post_b, q_w);
}